// Round 1
// baseline (429.948 us; speedup 1.0000x reference)
//
#include <hip/hip_runtime.h>

typedef unsigned int u32;
typedef unsigned short u16;
typedef __attribute__((ext_vector_type(8))) short bf16x8;   // 8 bf16 in 4 VGPRs
typedef __attribute__((ext_vector_type(4))) float f32x4;

#define DF 128
#define NBUCK 256          // max buckets (dst >> 9), N=100k -> 196 used
#define BUCK_SHIFT 9
#define BUCK_SIZE 512
#define P2_CHUNK 4096      // 16 edges per thread, 256 threads
#define NCOPY 16           // stat atomic spreading factor
#define STATW (NCOPY * DF)

__device__ __forceinline__ float bf2f(u32 h) { return __uint_as_float(h << 16); }
__device__ __forceinline__ u16 f2bf(float f) {
  u32 u = __float_as_uint(f);
  u32 r = (u + 0x7fffu + ((u >> 16) & 1u)) >> 16;   // RNE
  return (u16)r;
}
__device__ __forceinline__ u32 pack2(float a, float b) {
  return (u32)f2bf(a) | ((u32)f2bf(b) << 16);
}

// ---------- generic f32 -> bf16 conversion (x, W1, W2) ----------
__global__ void k_cvt_f32_bf16(const float* __restrict__ in, u16* __restrict__ out, int n4) {
  int i = blockIdx.x * blockDim.x + threadIdx.x;
  if (i >= n4) return;
  float4 v = ((const float4*)in)[i];
  ((uint2*)out)[i] = make_uint2(pack2(v.x, v.y), pack2(v.z, v.w));
}

// ---------- CSR build via bucketed counting sort ----------
__global__ __launch_bounds__(256) void k_p1(const int* __restrict__ dst,
                                            int* __restrict__ bucketCount, int E) {
  __shared__ int h[NBUCK];
  int t = threadIdx.x;
  h[t] = 0;
  __syncthreads();
  for (int e = blockIdx.x * 256 + t; e < E; e += gridDim.x * 256)
    atomicAdd(&h[((u32)dst[e]) >> BUCK_SHIFT], 1);
  __syncthreads();
  if (h[t]) atomicAdd(&bucketCount[t], h[t]);
}

__global__ __launch_bounds__(256) void k_pscan(const int* __restrict__ bucketCount,
                                               int* __restrict__ bucketStart,
                                               int* __restrict__ bucketCursor,
                                               int* __restrict__ rowptr, int N, int E) {
  __shared__ int sh[NBUCK];
  int t = threadIdx.x;
  int c = bucketCount[t];
  sh[t] = c;
  __syncthreads();
  for (int o = 1; o < 256; o <<= 1) {
    int v = (t >= o) ? sh[t - o] : 0;
    __syncthreads();
    sh[t] += v;
    __syncthreads();
  }
  int excl = sh[t] - c;
  bucketStart[t] = excl;
  bucketCursor[t] = excl;
  if (t == 255) { bucketStart[256] = sh[255]; rowptr[N] = E; }
}

__global__ __launch_bounds__(256) void k_p2(const int* __restrict__ src,
                                            const int* __restrict__ dst,
                                            int* __restrict__ bucketCursor,
                                            uint2* __restrict__ part, int E) {
  __shared__ int h[NBUCK], hs[NBUCK], base[NBUCK];
  __shared__ int total;
  __shared__ uint2 buf[P2_CHUNK];
  int t = threadIdx.x;
  int e0 = blockIdx.x * P2_CHUNK;
  h[t] = 0;
  __syncthreads();
  int myb[16], myr[16];
  uint2 mye[16];
  #pragma unroll
  for (int k = 0; k < 16; k++) {
    int e = e0 + k * 256 + t;
    myb[k] = -1;
    if (e < E) {
      int s = src[e], d = dst[e];
      mye[k] = make_uint2((u32)s, (u32)d);
      myb[k] = ((u32)d) >> BUCK_SHIFT;
      myr[k] = atomicAdd(&h[myb[k]], 1);
    }
  }
  __syncthreads();
  int hc = h[t];
  hs[t] = hc;
  __syncthreads();
  for (int o = 1; o < 256; o <<= 1) {
    int v = (t >= o) ? hs[t - o] : 0;
    __syncthreads();
    hs[t] += v;
    __syncthreads();
  }
  if (t == 255) total = hs[255];
  int excl = hs[t] - hc;
  base[t] = hc ? atomicAdd(&bucketCursor[t], hc) : 0;
  __syncthreads();
  hs[t] = excl;
  __syncthreads();
  #pragma unroll
  for (int k = 0; k < 16; k++)
    if (myb[k] >= 0) buf[hs[myb[k]] + myr[k]] = mye[k];
  __syncthreads();
  int tot = total;
  for (int i = t; i < tot; i += 256) {
    uint2 ed = buf[i];
    int b = ed.y >> BUCK_SHIFT;
    part[base[b] + (i - hs[b])] = ed;
  }
}

__global__ __launch_bounds__(256) void k_p3(const uint2* __restrict__ part,
                                            const int* __restrict__ bucketStart,
                                            int* __restrict__ rowptr,
                                            int* __restrict__ adj, int N) {
  __shared__ int deg[BUCK_SIZE], cur[BUCK_SIZE], psum[256];
  int b = blockIdx.x, t = threadIdx.x;
  int nodeBase = b << BUCK_SHIFT;
  int eb = bucketStart[b], ee = bucketStart[b + 1];
  deg[t] = 0; deg[t + 256] = 0;
  __syncthreads();
  for (int e = eb + t; e < ee; e += 256)
    atomicAdd(&deg[(int)part[e].y - nodeBase], 1);
  __syncthreads();
  int a0 = deg[2 * t], a1 = deg[2 * t + 1];
  psum[t] = a0 + a1;
  __syncthreads();
  for (int o = 1; o < 256; o <<= 1) {
    int v = (t >= o) ? psum[t - o] : 0;
    __syncthreads();
    psum[t] += v;
    __syncthreads();
  }
  int basep = psum[t] - (a0 + a1);
  int p0 = eb + basep, p1 = eb + basep + a0;
  cur[2 * t] = p0; cur[2 * t + 1] = p1;
  int n0 = nodeBase + 2 * t, n1 = nodeBase + 2 * t + 1;
  if (n0 < N) rowptr[n0] = p0;
  if (n1 < N) rowptr[n1] = p1;
  __syncthreads();
  for (int e = eb + t; e < ee; e += 256) {
    uint2 ed = part[e];
    int pos = atomicAdd(&cur[(int)ed.y - nodeBase], 1);
    adj[pos] = (int)ed.x;
  }
}

// ---------- aggregation with fused inter-layer BN+ReLU ----------
// Input hin is the PRE-BN activation u of the previous stage (or Xb at l=0).
// Effective node feature: t(v) = relu(a*v + c)   (a=1,c=0 at l=0; selfRelu=0 at l=0)
//   z = (1+eps)*t_self(hin[n]) + sum_{e:dst==n} t(hin[src])
// Masked neighbor slots load v=0 contributing max(c,0) each; counted in `inv`
// and subtracted after the loop (exact at l=0 where c=0; ulp-level otherwise).
// One wave per node; 16 lanes per neighbor row (uint4 = 8 feats/lane), 2x unrolled.
__global__ void k_aggr(const u16* __restrict__ hin,
                       const int* __restrict__ rowptr, const int* __restrict__ adj,
                       const float* __restrict__ epsArr, int layer,
                       const float* __restrict__ aAff, const float* __restrict__ cAff,
                       int selfRelu,
                       u16* __restrict__ z, int N) {
  int wid = (blockIdx.x * blockDim.x + threadIdx.x) >> 6;
  if (wid >= N) return;
  int lane = threadIdx.x & 63;
  int g = lane >> 4, f = lane & 15;          // neighbor slot, feature group
  const uint4* h4 = (const uint4*)hin;
  float e1 = 1.0f + epsArr[layer];

  float av[8], cv[8];
  if (aAff) {
    float4 a0 = *(const float4*)(aAff + f * 8);
    float4 a1 = *(const float4*)(aAff + f * 8 + 4);
    float4 c0 = *(const float4*)(cAff + f * 8);
    float4 c1 = *(const float4*)(cAff + f * 8 + 4);
    av[0] = a0.x; av[1] = a0.y; av[2] = a0.z; av[3] = a0.w;
    av[4] = a1.x; av[5] = a1.y; av[6] = a1.z; av[7] = a1.w;
    cv[0] = c0.x; cv[1] = c0.y; cv[2] = c0.z; cv[3] = c0.w;
    cv[4] = c1.x; cv[5] = c1.y; cv[6] = c1.z; cv[7] = c1.w;
  } else {
    #pragma unroll
    for (int k = 0; k < 8; k++) { av[k] = 1.0f; cv[k] = 0.0f; }
  }

  float acc[8];
  #pragma unroll
  for (int k = 0; k < 8; k++) acc[k] = 0.0f;

  // self term, group 0 only
  if (g == 0) {
    uint4 v = h4[(size_t)wid * 16 + f];
    u32 w[4] = {v.x, v.y, v.z, v.w};
    #pragma unroll
    for (int k = 0; k < 4; k++) {
      float lo = fmaf(av[2 * k],     __uint_as_float(w[k] << 16),         cv[2 * k]);
      float hi = fmaf(av[2 * k + 1], __uint_as_float(w[k] & 0xffff0000u), cv[2 * k + 1]);
      if (selfRelu) { lo = fmaxf(lo, 0.0f); hi = fmaxf(hi, 0.0f); }
      acc[2 * k]     = e1 * lo;
      acc[2 * k + 1] = e1 * hi;
    }
  }

  int b = rowptr[wid], e = rowptr[wid + 1];
  int inv = 0;
  for (int p = b; p < e; p += 8) {
    int i0 = p + g, i1 = p + 4 + g;
    uint4 v0 = make_uint4(0, 0, 0, 0), v1 = make_uint4(0, 0, 0, 0);
    if (i0 < e) v0 = h4[(size_t)(u32)adj[i0] * 16 + f]; else inv++;
    if (i1 < e) v1 = h4[(size_t)(u32)adj[i1] * 16 + f]; else inv++;
    u32 w0[4] = {v0.x, v0.y, v0.z, v0.w};
    u32 w1[4] = {v1.x, v1.y, v1.z, v1.w};
    #pragma unroll
    for (int k = 0; k < 4; k++) {
      acc[2 * k]     += fmaxf(fmaf(av[2 * k],     __uint_as_float(w0[k] << 16),         cv[2 * k]),     0.0f);
      acc[2 * k + 1] += fmaxf(fmaf(av[2 * k + 1], __uint_as_float(w0[k] & 0xffff0000u), cv[2 * k + 1]), 0.0f);
      acc[2 * k]     += fmaxf(fmaf(av[2 * k],     __uint_as_float(w1[k] << 16),         cv[2 * k]),     0.0f);
      acc[2 * k + 1] += fmaxf(fmaf(av[2 * k + 1], __uint_as_float(w1[k] & 0xffff0000u), cv[2 * k + 1]), 0.0f);
    }
  }
  // remove contribution of zero-filled invalid slots: each added max(c,0)
  float cinv = (float)inv;
  #pragma unroll
  for (int k = 0; k < 8; k++) acc[k] -= cinv * fmaxf(cv[k], 0.0f);

  // reduce across the 4 neighbor slots
  #pragma unroll
  for (int k = 0; k < 8; k++) {
    acc[k] += __shfl_xor(acc[k], 16);
    acc[k] += __shfl_xor(acc[k], 32);
  }
  if (g == 0) {
    uint4 o = make_uint4(pack2(acc[0], acc[1]), pack2(acc[2], acc[3]),
                         pack2(acc[4], acc[5]), pack2(acc[6], acc[7]));
    ((uint4*)z)[(size_t)wid * 16 + f] = o;
  }
}

// ---------- GEMM: out[r][c] = sum_k in[r][k] * W[c][k] + bias[c]  (bf16 MFMA) ----------
// trans=1: fused BN finalize preamble (from Sprev/Qprev stats + gamma/beta) computes
// per-feature affine (a,c) into LDS, then input transform in' = relu(a[k]*in + c[k])
// is applied during A-staging. Eliminates the separate k_finalize dispatch.
// stats: per-wave shfl reduce, then atomics spread over NCOPY copies (blockIdx&15)
__global__ __launch_bounds__(256, 2) void k_gemm(
    const u16* __restrict__ A, const u16* __restrict__ W, const float* __restrict__ bias,
    const float* __restrict__ Sprev, const float* __restrict__ Qprev,
    const float* __restrict__ gprev, const float* __restrict__ btprev, int trans,
    float* __restrict__ statS, float* __restrict__ statQ,
    u16* __restrict__ out, int Nrows) {
  __shared__ u16 lA[4 * 8 * 64 * 8];  // 32 KB
  __shared__ u16 lB[4 * 8 * 64 * 8];  // 32 KB
  __shared__ float sAf[DF], sCf[DF];
  int tid = threadIdx.x;
  int rowBase = blockIdx.x * 128;

  if (trans) {
    if (tid < DF) {
      float Sv = 0.f, Qv = 0.f;
      #pragma unroll
      for (int i = 0; i < NCOPY; i++) { Sv += Sprev[i * DF + tid]; Qv += Qprev[i * DF + tid]; }
      float inv_n = 1.0f / (float)Nrows;
      float mean = Sv * inv_n;
      float var = fmaxf(Qv * inv_n - mean * mean, 0.0f);
      float iv = rsqrtf(var + 1e-5f);
      float a = gprev[tid] * iv;
      sAf[tid] = a;
      sCf[tid] = btprev[tid] - mean * a;
    }
    __syncthreads();
  }

  // stage A (z rows) in fragment order
  #pragma unroll
  for (int cc = 0; cc < 8; cc++) {
    int c = tid + cc * 256;
    int lane = c & 63, rt = (c >> 6) & 7, kt = c >> 9;
    int m = lane & 15, quad = lane >> 4;
    int grow = rowBase + rt * 16 + m;
    int gk = kt * 32 + quad * 8;
    uint4 val = make_uint4(0, 0, 0, 0);
    if (grow < Nrows) val = *(const uint4*)(A + (size_t)grow * DF + gk);
    if (trans) {
      float4 av0 = *(const float4*)(sAf + gk);
      float4 av1 = *(const float4*)(sAf + gk + 4);
      float4 cv0 = *(const float4*)(sCf + gk);
      float4 cv1 = *(const float4*)(sCf + gk + 4);
      float f0 = fmaxf(fmaf(av0.x, bf2f(val.x & 0xffffu), cv0.x), 0.0f);
      float f1 = fmaxf(fmaf(av0.y, bf2f(val.x >> 16),     cv0.y), 0.0f);
      float f2 = fmaxf(fmaf(av0.z, bf2f(val.y & 0xffffu), cv0.z), 0.0f);
      float f3 = fmaxf(fmaf(av0.w, bf2f(val.y >> 16),     cv0.w), 0.0f);
      float f4 = fmaxf(fmaf(av1.x, bf2f(val.z & 0xffffu), cv1.x), 0.0f);
      float f5 = fmaxf(fmaf(av1.y, bf2f(val.z >> 16),     cv1.y), 0.0f);
      float f6 = fmaxf(fmaf(av1.z, bf2f(val.w & 0xffffu), cv1.z), 0.0f);
      float f7 = fmaxf(fmaf(av1.w, bf2f(val.w >> 16),     cv1.w), 0.0f);
      val = make_uint4(pack2(f0, f1), pack2(f2, f3), pack2(f4, f5), pack2(f6, f7));
    }
    ((uint4*)lA)[c] = val;
  }
  // stage B (W rows, [c][k]) in fragment order
  #pragma unroll
  for (int cc = 0; cc < 8; cc++) {
    int c = tid + cc * 256;
    int lane = c & 63, ct = (c >> 6) & 7, kt = c >> 9;
    int n = lane & 15, quad = lane >> 4;
    ((uint4*)lB)[c] = *(const uint4*)(W + (ct * 16 + n) * DF + kt * 32 + quad * 8);
  }
  __syncthreads();

  int lane = tid & 63, w = tid >> 6;
  int rq = w >> 1, cq = w & 1;  // wave -> 64x64 quadrant
  f32x4 acc[4][4];
  #pragma unroll
  for (int i = 0; i < 4; i++)
    #pragma unroll
    for (int j = 0; j < 4; j++) acc[i][j] = (f32x4){0.f, 0.f, 0.f, 0.f};

  const bf16x8* pA = (const bf16x8*)lA;
  const bf16x8* pB = (const bf16x8*)lB;
  #pragma unroll
  for (int kt = 0; kt < 4; kt++) {
    bf16x8 af[4], bfr[4];
    #pragma unroll
    for (int i = 0; i < 4; i++) af[i] = pA[(kt * 8 + rq * 4 + i) * 64 + lane];
    #pragma unroll
    for (int j = 0; j < 4; j++) bfr[j] = pB[(kt * 8 + cq * 4 + j) * 64 + lane];
    #pragma unroll
    for (int i = 0; i < 4; i++)
      #pragma unroll
      for (int j = 0; j < 4; j++)
        acc[i][j] = __builtin_amdgcn_mfma_f32_16x16x32_bf16(af[i], bfr[j], acc[i][j], 0, 0, 0);
  }

  // epilogue: bias, store bf16, per-column stats
  int mcol = lane & 15, quad = lane >> 4;
  float colS[4] = {0, 0, 0, 0}, colQ[4] = {0, 0, 0, 0};
  #pragma unroll
  for (int j = 0; j < 4; j++) {
    int col = (cq * 4 + j) * 16 + mcol;
    float bv = bias[col];
    #pragma unroll
    for (int i = 0; i < 4; i++) {
      int row0 = rowBase + (rq * 4 + i) * 16 + quad * 4;
      #pragma unroll
      for (int r = 0; r < 4; r++) {
        int row = row0 + r;
        if (row < Nrows) {
          float v = acc[i][j][r] + bv;
          out[(size_t)row * DF + col] = f2bf(v);
          colS[j] += v;
          colQ[j] += v * v;
        }
      }
    }
  }
  int copyOff = (blockIdx.x & (NCOPY - 1)) * DF;
  #pragma unroll
  for (int j = 0; j < 4; j++) {
    float s = colS[j], q = colQ[j];
    s += __shfl_xor(s, 16); q += __shfl_xor(q, 16);
    s += __shfl_xor(s, 32); q += __shfl_xor(q, 32);
    if (quad == 0) {
      int col = (cq * 4 + j) * 16 + mcol;
      atomicAdd(&statS[copyOff + col], s);
      atomicAdd(&statQ[copyOff + col], q);
    }
  }
}

// ---------- finalize BN stats (sum NCOPY copies) into affine a,c ----------
// (still used once per non-final layer: a,c consumed by the next layer's k_aggr)
__global__ void k_finalize(const float* __restrict__ s, const float* __restrict__ q,
                           const float* __restrict__ gamma, const float* __restrict__ beta,
                           float* __restrict__ a, float* __restrict__ c, int Nrows) {
  int t = threadIdx.x;
  if (t < DF) {
    float S = 0.f, Q = 0.f;
    #pragma unroll
    for (int i = 0; i < NCOPY; i++) { S += s[i * DF + t]; Q += q[i * DF + t]; }
    float inv_n = 1.0f / (float)Nrows;
    float mean = S * inv_n;
    float var = fmaxf(Q * inv_n - mean * mean, 0.0f);
    float iv = rsqrtf(var + 1e-5f);
    float av = gamma[t] * iv;
    a[t] = av;
    c[t] = beta[t] - mean * av;
  }
}

// ---------- final BN apply, f32 out, fused finalize, grid-stride ----------
__global__ __launch_bounds__(256) void k_bnout_f32(
    const u16* __restrict__ u, const float* __restrict__ S, const float* __restrict__ Q,
    const float* __restrict__ gamma, const float* __restrict__ beta, int Nrows,
    float* __restrict__ out, int n8) {
  __shared__ float sAf[DF], sCf[DF];
  int tid = threadIdx.x;
  if (tid < DF) {
    float Sv = 0.f, Qv = 0.f;
    #pragma unroll
    for (int i = 0; i < NCOPY; i++) { Sv += S[i * DF + tid]; Qv += Q[i * DF + tid]; }
    float inv_n = 1.0f / (float)Nrows;
    float mean = Sv * inv_n;
    float var = fmaxf(Qv * inv_n - mean * mean, 0.0f);
    float iv = rsqrtf(var + 1e-5f);
    float a = gamma[tid] * iv;
    sAf[tid] = a;
    sCf[tid] = beta[tid] - mean * a;
  }
  __syncthreads();
  for (int i = blockIdx.x * 256 + tid; i < n8; i += gridDim.x * 256) {
    int col = (i * 8) & 127;
    float4 a0 = *(const float4*)(sAf + col), a1v = *(const float4*)(sAf + col + 4);
    float4 c0 = *(const float4*)(sCf + col), c1v = *(const float4*)(sCf + col + 4);
    uint4 v = ((const uint4*)u)[i];
    float4 o0, o1;
    o0.x = fmaf(a0.x, bf2f(v.x & 0xffffu), c0.x);
    o0.y = fmaf(a0.y, bf2f(v.x >> 16),     c0.y);
    o0.z = fmaf(a0.z, bf2f(v.y & 0xffffu), c0.z);
    o0.w = fmaf(a0.w, bf2f(v.y >> 16),     c0.w);
    o1.x = fmaf(a1v.x, bf2f(v.z & 0xffffu), c1v.x);
    o1.y = fmaf(a1v.y, bf2f(v.z >> 16),     c1v.y);
    o1.z = fmaf(a1v.z, bf2f(v.w & 0xffffu), c1v.z);
    o1.w = fmaf(a1v.w, bf2f(v.w >> 16),     c1v.w);
    ((float4*)out)[i * 2] = o0;
    ((float4*)out)[i * 2 + 1] = o1;
  }
}

extern "C" void kernel_launch(void* const* d_in, const int* in_sizes, int n_in,
                              void* d_out, int out_size, void* d_ws, size_t ws_size,
                              hipStream_t stream) {
  const float* x    = (const float*)d_in[0];
  const int*   ei   = (const int*)d_in[1];
  const float* W1   = (const float*)d_in[2];
  const float* b1   = (const float*)d_in[3];
  const float* g1   = (const float*)d_in[4];
  const float* bt1  = (const float*)d_in[5];
  const float* W2   = (const float*)d_in[6];
  const float* b2   = (const float*)d_in[7];
  const float* eps  = (const float*)d_in[8];
  const float* gout = (const float*)d_in[9];
  const float* btout= (const float*)d_in[10];

  int N = in_sizes[0] / DF;
  int E = in_sizes[1] / 2;
  int L = in_sizes[8];

  char* ws = (char*)d_ws;
  size_t off = 0;
  auto alloc = [&](size_t bytes) -> void* {
    void* p = ws + off;
    off += (bytes + 255) & ~(size_t)255;
    return p;
  };
  u16* Xb     = (u16*)alloc((size_t)N * DF * 2);
  u16* bufA   = (u16*)alloc((size_t)N * DF * 2);
  u16* bufB   = (u16*)alloc((size_t)N * DF * 2);
  int* rowptr = (int*)alloc((size_t)(N + 1) * 4);
  int* adj    = (int*)alloc((size_t)E * 4);
  uint2* part = (uint2*)alloc((size_t)E * 8);
  int* bCount = (int*)alloc(NBUCK * 4);
  int* bStart = (int*)alloc((NBUCK + 1) * 4);
  int* bCur   = (int*)alloc(NBUCK * 4);
  u16* W1b    = (u16*)alloc((size_t)L * DF * DF * 2);
  u16* W2b    = (u16*)alloc((size_t)L * DF * DF * 2);
  float* stats= (float*)alloc((size_t)L * 4 * STATW * 4);
  float* coefs= (float*)alloc((size_t)L * 4 * DF * 4);

  hipMemsetAsync(bCount, 0, NBUCK * 4, stream);
  hipMemsetAsync(stats, 0, (size_t)L * 4 * STATW * 4, stream);

  int n4x = N * DF / 4;
  k_cvt_f32_bf16<<<(n4x + 255) / 256, 256, 0, stream>>>(x, Xb, n4x);
  int n4w = L * DF * DF / 4;
  k_cvt_f32_bf16<<<(n4w + 255) / 256, 256, 0, stream>>>(W1, W1b, n4w);
  k_cvt_f32_bf16<<<(n4w + 255) / 256, 256, 0, stream>>>(W2, W2b, n4w);

  const int* srcI = ei;
  const int* dstI = ei + E;
  int nbuckets = (N + BUCK_SIZE - 1) >> BUCK_SHIFT;
  k_p1<<<512, 256, 0, stream>>>(dstI, bCount, E);
  k_pscan<<<1, 256, 0, stream>>>(bCount, bStart, bCur, rowptr, N, E);
  k_p2<<<(E + P2_CHUNK - 1) / P2_CHUNK, 256, 0, stream>>>(srcI, dstI, bCur, part, E);
  k_p3<<<nbuckets, 256, 0, stream>>>(part, bStart, rowptr, adj, N);

  // Buffer plan per layer l (z/t/u ping-pong, fused inter-layer BN in aggr):
  //   l even: aggr: H -> bufA(z); gemm1: bufA -> bufB(t); gemm2: bufB -> bufA(u)
  //   l odd : aggr: H -> bufB(z); gemm1: bufB -> bufA(t); gemm2: bufA -> bufB(u)
  // H for l=0 is Xb (selfRelu=0, identity affine); for l>0 H is the previous u
  // with affine (aPrev,cPrev) = previous layer's outer-BN coefs, selfRelu=1.
  int gblocks = (N + 127) / 128;
  int n8 = N * DF / 8;
  const u16* Hcur = Xb;
  const float* aPrev = nullptr;
  const float* cPrev = nullptr;
  int selfRelu = 0;
  for (int l = 0; l < L; l++) {
    float* S1 = stats + (size_t)(l * 4 + 0) * STATW;
    float* Q1 = stats + (size_t)(l * 4 + 1) * STATW;
    float* S2 = stats + (size_t)(l * 4 + 2) * STATW;
    float* Q2 = stats + (size_t)(l * 4 + 3) * STATW;
    float* a2 = coefs + (size_t)(l * 4 + 2) * DF;
    float* c2 = coefs + (size_t)(l * 4 + 3) * DF;
    u16* z = (l & 1) ? bufB : bufA;
    u16* t = (l & 1) ? bufA : bufB;
    u16* u = z;  // z is dead once gemm1 consumed it

    // z = (1+eps)*t_self(H) + sum t(H[src]),  t = relu(a*. + c)
    k_aggr<<<(N + 3) / 4, 256, 0, stream>>>(Hcur, rowptr, adj, eps, l,
                                            aPrev, cPrev, selfRelu, z, N);
    // t = z @ W1^T + b1, stats S1/Q1
    k_gemm<<<gblocks, 256, 0, stream>>>(z, W1b + l * DF * DF, b1 + l * DF,
                                        nullptr, nullptr, nullptr, nullptr, 0,
                                        S1, Q1, t, N);
    // u = relu(BN1(t)) @ W2^T + b2 (BN1 finalize fused in preamble), stats S2/Q2
    k_gemm<<<gblocks, 256, 0, stream>>>(t, W2b + l * DF * DF, b2 + l * DF,
                                        S1, Q1, g1 + l * DF, bt1 + l * DF, 1,
                                        S2, Q2, u, N);
    if (l < L - 1) {
      // outer-BN coefs for the next layer's fused aggr
      k_finalize<<<1, 128, 0, stream>>>(S2, Q2, gout + l * DF, btout + l * DF, a2, c2, N);
      aPrev = a2; cPrev = c2; selfRelu = 1;
      Hcur = u;
    } else {
      k_bnout_f32<<<2048, 256, 0, stream>>>(u, S2, Q2, gout + l * DF, btout + l * DF,
                                            N, (float*)d_out, n8);
    }
  }
}

// Round 4
// 370.684 us; speedup vs baseline: 1.1599x; 1.1599x over previous
//
#include <hip/hip_runtime.h>
#include <hip/hip_fp16.h>

typedef unsigned int u32;
typedef unsigned short u16;
typedef __attribute__((ext_vector_type(8))) _Float16 f16x8;  // 8 fp16 in 4 VGPRs
typedef __attribute__((ext_vector_type(4))) float f32x4;

#define DF 128
#define NBUCK 256          // max buckets (dst >> 9), N=100k -> 196 used
#define BUCK_SHIFT 9
#define BUCK_SIZE 512
#define P2_CHUNK 4096      // 16 edges per thread, 256 threads
#define NCOPY 16           // stat atomic spreading factor
#define STATW (NCOPY * DF)
#define CSTRIDE 132        // f32 stride for C staging (16B-aligned rows, ~2-way banks)

__device__ __forceinline__ __half2 u2h2(u32 x) { union { u32 u; __half2 h; } v; v.u = x; return v.h; }
__device__ __forceinline__ u32 h22u(__half2 h) { union { u32 u; __half2 h; } v; v.h = h; return v.u; }
__device__ __forceinline__ u32 pack2h(float a, float b) { return h22u(__floats2half2_rn(a, b)); }

// packed fp16 max via v_pk_max_f16 (ROCm 7.2 hip_fp16.h lacks __hmax2 on this target)
__device__ __forceinline__ u32 pkmax_u(u32 a, u32 b) {
  u32 r;
  asm("v_pk_max_f16 %0, %1, %2" : "=v"(r) : "v"(a), "v"(b));
  return r;
}
__device__ __forceinline__ __half2 hmax2(__half2 a, __half2 b) {
  return u2h2(pkmax_u(h22u(a), h22u(b)));
}

// ---------- generic f32 -> fp16 conversion (x, W1, W2) ----------
__global__ void k_cvt_f32_f16(const float* __restrict__ in, u16* __restrict__ out, int n4) {
  int i = blockIdx.x * blockDim.x + threadIdx.x;
  if (i >= n4) return;
  float4 v = ((const float4*)in)[i];
  ((uint2*)out)[i] = make_uint2(pack2h(v.x, v.y), pack2h(v.z, v.w));
}

// ---------- CSR build via bucketed counting sort ----------
__global__ __launch_bounds__(256) void k_p1(const int* __restrict__ dst,
                                            int* __restrict__ bucketCount, int E) {
  __shared__ int h[NBUCK];
  int t = threadIdx.x;
  h[t] = 0;
  __syncthreads();
  for (int e = blockIdx.x * 256 + t; e < E; e += gridDim.x * 256)
    atomicAdd(&h[((u32)dst[e]) >> BUCK_SHIFT], 1);
  __syncthreads();
  if (h[t]) atomicAdd(&bucketCount[t], h[t]);
}

__global__ __launch_bounds__(256) void k_pscan(const int* __restrict__ bucketCount,
                                               int* __restrict__ bucketStart,
                                               int* __restrict__ bucketCursor,
                                               int* __restrict__ rowptr, int N, int E) {
  __shared__ int sh[NBUCK];
  int t = threadIdx.x;
  int c = bucketCount[t];
  sh[t] = c;
  __syncthreads();
  for (int o = 1; o < 256; o <<= 1) {
    int v = (t >= o) ? sh[t - o] : 0;
    __syncthreads();
    sh[t] += v;
    __syncthreads();
  }
  int excl = sh[t] - c;
  bucketStart[t] = excl;
  bucketCursor[t] = excl;
  if (t == 255) { bucketStart[256] = sh[255]; rowptr[N] = E; }
}

__global__ __launch_bounds__(256) void k_p2(const int* __restrict__ src,
                                            const int* __restrict__ dst,
                                            int* __restrict__ bucketCursor,
                                            uint2* __restrict__ part, int E) {
  __shared__ int h[NBUCK], hs[NBUCK], base[NBUCK];
  __shared__ int total;
  __shared__ uint2 buf[P2_CHUNK];
  int t = threadIdx.x;
  int e0 = blockIdx.x * P2_CHUNK;
  h[t] = 0;
  __syncthreads();
  int myb[16], myr[16];
  uint2 mye[16];
  #pragma unroll
  for (int k = 0; k < 16; k++) {
    int e = e0 + k * 256 + t;
    myb[k] = -1;
    if (e < E) {
      int s = src[e], d = dst[e];
      mye[k] = make_uint2((u32)s, (u32)d);
      myb[k] = ((u32)d) >> BUCK_SHIFT;
      myr[k] = atomicAdd(&h[myb[k]], 1);
    }
  }
  __syncthreads();
  int hc = h[t];
  hs[t] = hc;
  __syncthreads();
  for (int o = 1; o < 256; o <<= 1) {
    int v = (t >= o) ? hs[t - o] : 0;
    __syncthreads();
    hs[t] += v;
    __syncthreads();
  }
  if (t == 255) total = hs[255];
  int excl = hs[t] - hc;
  base[t] = hc ? atomicAdd(&bucketCursor[t], hc) : 0;
  __syncthreads();
  hs[t] = excl;
  __syncthreads();
  #pragma unroll
  for (int k = 0; k < 16; k++)
    if (myb[k] >= 0) buf[hs[myb[k]] + myr[k]] = mye[k];
  __syncthreads();
  int tot = total;
  for (int i = t; i < tot; i += 256) {
    uint2 ed = buf[i];
    int b = ed.y >> BUCK_SHIFT;
    part[base[b] + (i - hs[b])] = ed;
  }
}

__global__ __launch_bounds__(256) void k_p3(const uint2* __restrict__ part,
                                            const int* __restrict__ bucketStart,
                                            int* __restrict__ rowptr,
                                            int* __restrict__ adj, int N) {
  __shared__ int deg[BUCK_SIZE], cur[BUCK_SIZE], psum[256];
  int b = blockIdx.x, t = threadIdx.x;
  int nodeBase = b << BUCK_SHIFT;
  int eb = bucketStart[b], ee = bucketStart[b + 1];
  deg[t] = 0; deg[t + 256] = 0;
  __syncthreads();
  for (int e = eb + t; e < ee; e += 256)
    atomicAdd(&deg[(int)part[e].y - nodeBase], 1);
  __syncthreads();
  int a0 = deg[2 * t], a1 = deg[2 * t + 1];
  psum[t] = a0 + a1;
  __syncthreads();
  for (int o = 1; o < 256; o <<= 1) {
    int v = (t >= o) ? psum[t - o] : 0;
    __syncthreads();
    psum[t] += v;
    __syncthreads();
  }
  int basep = psum[t] - (a0 + a1);
  int p0 = eb + basep, p1 = eb + basep + a0;
  cur[2 * t] = p0; cur[2 * t + 1] = p1;
  int n0 = nodeBase + 2 * t, n1 = nodeBase + 2 * t + 1;
  if (n0 < N) rowptr[n0] = p0;
  if (n1 < N) rowptr[n1] = p1;
  __syncthreads();
  for (int e = eb + t; e < ee; e += 256) {
    uint2 ed = part[e];
    int pos = atomicAdd(&cur[(int)ed.y - nodeBase], 1);
    adj[pos] = (int)ed.x;
  }
}

// ---------- aggregation with fused inter-layer BN+ReLU (packed fp16) ----------
// Input hin is the PRE-BN activation u of the previous stage (or Xb at l=0).
// Effective node feature: t(v) = relu(a*v + c)   (a=1,c=0 at l=0; selfRelu=0 at l=0)
//   z = (1+eps)*t_self(hin[n]) + sum_{e:dst==n} t(hin[src])
// Neighbor transform+accumulate runs fully packed (v_pk_fma/max/add_f16).
// Masked slots load 0 contributing max(c,0); counted in inv, subtracted packed.
// Self term + (1+eps) scale done in f32 per node (fixed cost).
__global__ void k_aggr(const u16* __restrict__ hin,
                       const int* __restrict__ rowptr, const int* __restrict__ adj,
                       const float* __restrict__ epsArr, int layer,
                       const float* __restrict__ aAff, const float* __restrict__ cAff,
                       int selfRelu,
                       u16* __restrict__ z, int N) {
  int wid = (blockIdx.x * blockDim.x + threadIdx.x) >> 6;
  if (wid >= N) return;
  int lane = threadIdx.x & 63;
  int g = lane >> 4, f = lane & 15;          // neighbor slot, feature group
  const uint4* h4 = (const uint4*)hin;
  float e1 = 1.0f + epsArr[layer];
  __half2 zero2 = __floats2half2_rn(0.0f, 0.0f);

  float av[8], cv[8];
  if (aAff) {
    float4 a0 = *(const float4*)(aAff + f * 8);
    float4 a1 = *(const float4*)(aAff + f * 8 + 4);
    float4 c0 = *(const float4*)(cAff + f * 8);
    float4 c1 = *(const float4*)(cAff + f * 8 + 4);
    av[0] = a0.x; av[1] = a0.y; av[2] = a0.z; av[3] = a0.w;
    av[4] = a1.x; av[5] = a1.y; av[6] = a1.z; av[7] = a1.w;
    cv[0] = c0.x; cv[1] = c0.y; cv[2] = c0.z; cv[3] = c0.w;
    cv[4] = c1.x; cv[5] = c1.y; cv[6] = c1.z; cv[7] = c1.w;
  } else {
    #pragma unroll
    for (int k = 0; k < 8; k++) { av[k] = 1.0f; cv[k] = 0.0f; }
  }
  __half2 a2[4], c2[4], cm2[4], acc2[4];
  #pragma unroll
  for (int k = 0; k < 4; k++) {
    a2[k] = __floats2half2_rn(av[2 * k], av[2 * k + 1]);
    c2[k] = __floats2half2_rn(cv[2 * k], cv[2 * k + 1]);
    cm2[k] = hmax2(c2[k], zero2);
    acc2[k] = zero2;
  }

  int b = rowptr[wid], e = rowptr[wid + 1];
  int inv = 0;
  for (int p = b; p < e; p += 8) {
    int i0 = p + g, i1 = p + 4 + g;
    uint4 v0 = make_uint4(0, 0, 0, 0), v1 = make_uint4(0, 0, 0, 0);
    if (i0 < e) v0 = h4[(size_t)(u32)adj[i0] * 16 + f]; else inv++;
    if (i1 < e) v1 = h4[(size_t)(u32)adj[i1] * 16 + f]; else inv++;
    u32 w0[4] = {v0.x, v0.y, v0.z, v0.w};
    u32 w1[4] = {v1.x, v1.y, v1.z, v1.w};
    #pragma unroll
    for (int k = 0; k < 4; k++) {
      acc2[k] = __hadd2(acc2[k], hmax2(__hfma2(a2[k], u2h2(w0[k]), c2[k]), zero2));
      acc2[k] = __hadd2(acc2[k], hmax2(__hfma2(a2[k], u2h2(w1[k]), c2[k]), zero2));
    }
  }
  // remove contribution of zero-filled invalid slots (each added max(c,0)),
  // then reduce across the 4 neighbor slots, all packed
  __half2 inv2 = __floats2half2_rn((float)inv, (float)inv);
  #pragma unroll
  for (int k = 0; k < 4; k++) {
    acc2[k] = __hsub2(acc2[k], __hmul2(inv2, cm2[k]));
    acc2[k] = __hadd2(acc2[k], u2h2(__shfl_xor(h22u(acc2[k]), 16)));
    acc2[k] = __hadd2(acc2[k], u2h2(__shfl_xor(h22u(acc2[k]), 32)));
  }

  if (g == 0) {
    uint4 sv = h4[(size_t)wid * 16 + f];
    u32 sw[4] = {sv.x, sv.y, sv.z, sv.w};
    u32 o[4];
    #pragma unroll
    for (int k = 0; k < 4; k++) {
      float2 s = __half22float2(u2h2(sw[k]));
      float lo = fmaf(av[2 * k], s.x, cv[2 * k]);
      float hi = fmaf(av[2 * k + 1], s.y, cv[2 * k + 1]);
      if (selfRelu) { lo = fmaxf(lo, 0.0f); hi = fmaxf(hi, 0.0f); }
      float2 nb = __half22float2(acc2[k]);
      o[k] = pack2h(fmaf(e1, lo, nb.x), fmaf(e1, hi, nb.y));
    }
    ((uint4*)z)[(size_t)wid * 16 + f] = make_uint4(o[0], o[1], o[2], o[3]);
  }
}

// ---------- GEMM: out[r][c] = sum_k in[r][k] * W[c][k] + bias[c]  (fp16 MFMA) ----------
// trans=1: fused BN finalize preamble computes packed half2 affine into LDS; input
// transform in' = relu(a[k]*in + c[k]) applied packed during A-staging.
// Epilogue: C staged through LDS (f32, stride CSTRIDE) then stored as coalesced
// uint4 (8 stores/thread instead of 64 scalar 2B stores).
__global__ __launch_bounds__(256, 2) void k_gemm(
    const u16* __restrict__ A, const u16* __restrict__ W, const float* __restrict__ bias,
    const float* __restrict__ Sprev, const float* __restrict__ Qprev,
    const float* __restrict__ gprev, const float* __restrict__ btprev, int trans,
    float* __restrict__ statS, float* __restrict__ statQ,
    u16* __restrict__ out, int Nrows) {
  __shared__ __align__(16) char smem[128 * CSTRIDE * 4 + 512];
  u16* lA = (u16*)smem;                       // 32 KB (A tile, fp16)
  u16* lB = (u16*)(smem + 32768);             // 32 KB (B tile, fp16)
  float* sC = (float*)smem;                   // 128 x CSTRIDE f32 (epilogue reuse)
  __half2* sA2 = (__half2*)(smem + 128 * CSTRIDE * 4);        // 64 half2
  __half2* sC2 = (__half2*)(smem + 128 * CSTRIDE * 4 + 256);  // 64 half2
  int tid = threadIdx.x;
  int rowBase = blockIdx.x * 128;
  __half2 zero2 = __floats2half2_rn(0.0f, 0.0f);

  if (trans) {
    if (tid < 64) {
      float aa[2], cc[2];
      #pragma unroll
      for (int j = 0; j < 2; j++) {
        int col = tid * 2 + j;
        float Sv = 0.f, Qv = 0.f;
        #pragma unroll
        for (int i = 0; i < NCOPY; i++) { Sv += Sprev[i * DF + col]; Qv += Qprev[i * DF + col]; }
        float inv_n = 1.0f / (float)Nrows;
        float mean = Sv * inv_n;
        float var = fmaxf(Qv * inv_n - mean * mean, 0.0f);
        float iv = rsqrtf(var + 1e-5f);
        float a = gprev[col] * iv;
        aa[j] = a;
        cc[j] = btprev[col] - mean * a;
      }
      sA2[tid] = __floats2half2_rn(aa[0], aa[1]);
      sC2[tid] = __floats2half2_rn(cc[0], cc[1]);
    }
    __syncthreads();
  }

  // stage A (z rows) in fragment order
  #pragma unroll
  for (int cc = 0; cc < 8; cc++) {
    int c = tid + cc * 256;
    int lane = c & 63, rt = (c >> 6) & 7, kt = c >> 9;
    int m = lane & 15, quad = lane >> 4;
    int grow = rowBase + rt * 16 + m;
    int gk = kt * 32 + quad * 8;
    uint4 val = make_uint4(0, 0, 0, 0);
    if (grow < Nrows) val = *(const uint4*)(A + (size_t)grow * DF + gk);
    if (trans) {
      uint4 aw = ((const uint4*)sA2)[gk >> 3];
      uint4 cw = ((const uint4*)sC2)[gk >> 3];
      val.x = pkmax_u(h22u(__hfma2(u2h2(aw.x), u2h2(val.x), u2h2(cw.x))), 0u);
      val.y = pkmax_u(h22u(__hfma2(u2h2(aw.y), u2h2(val.y), u2h2(cw.y))), 0u);
      val.z = pkmax_u(h22u(__hfma2(u2h2(aw.z), u2h2(val.z), u2h2(cw.z))), 0u);
      val.w = pkmax_u(h22u(__hfma2(u2h2(aw.w), u2h2(val.w), u2h2(cw.w))), 0u);
    }
    ((uint4*)lA)[c] = val;
  }
  // stage B (W rows, [c][k]) in fragment order
  #pragma unroll
  for (int cc = 0; cc < 8; cc++) {
    int c = tid + cc * 256;
    int lane = c & 63, ct = (c >> 6) & 7, kt = c >> 9;
    int n = lane & 15, quad = lane >> 4;
    ((uint4*)lB)[c] = *(const uint4*)(W + (ct * 16 + n) * DF + kt * 32 + quad * 8);
  }
  __syncthreads();

  int lane = tid & 63, w = tid >> 6;
  int rq = w >> 1, cq = w & 1;  // wave -> 64x64 quadrant
  f32x4 acc[4][4];
  #pragma unroll
  for (int i = 0; i < 4; i++)
    #pragma unroll
    for (int j = 0; j < 4; j++) acc[i][j] = (f32x4){0.f, 0.f, 0.f, 0.f};

  const f16x8* pA = (const f16x8*)lA;
  const f16x8* pB = (const f16x8*)lB;
  #pragma unroll
  for (int kt = 0; kt < 4; kt++) {
    f16x8 af[4], bfr[4];
    #pragma unroll
    for (int i = 0; i < 4; i++) af[i] = pA[(kt * 8 + rq * 4 + i) * 64 + lane];
    #pragma unroll
    for (int j = 0; j < 4; j++) bfr[j] = pB[(kt * 8 + cq * 4 + j) * 64 + lane];
    #pragma unroll
    for (int i = 0; i < 4; i++)
      #pragma unroll
      for (int j = 0; j < 4; j++)
        acc[i][j] = __builtin_amdgcn_mfma_f32_16x16x32_f16(af[i], bfr[j], acc[i][j], 0, 0, 0);
  }

  __syncthreads();   // all LDS A/B reads done; safe to overwrite with C

  // epilogue: bias + per-column stats, C -> LDS (f32)
  int mcol = lane & 15, quad = lane >> 4;
  float colS[4] = {0, 0, 0, 0}, colQ[4] = {0, 0, 0, 0};
  #pragma unroll
  for (int j = 0; j < 4; j++) {
    int col = (cq * 4 + j) * 16 + mcol;
    float bv = bias[col];
    #pragma unroll
    for (int i = 0; i < 4; i++) {
      int rel0 = (rq * 4 + i) * 16 + quad * 4;
      #pragma unroll
      for (int r = 0; r < 4; r++) {
        int rel = rel0 + r;
        float v = acc[i][j][r] + bv;
        sC[rel * CSTRIDE + col] = v;
        if (rowBase + rel < Nrows) { colS[j] += v; colQ[j] += v * v; }
      }
    }
  }
  __syncthreads();

  // readout: coalesced fp16 uint4 stores (8 per thread)
  #pragma unroll
  for (int k = 0; k < 8; k++) {
    int idx = k * 256 + tid;          // uint4 index within 128x128 tile
    int rel = idx >> 4;
    int c0 = (idx & 15) * 8;
    int row = rowBase + rel;
    if (row < Nrows) {
      float4 x0 = *(const float4*)(sC + rel * CSTRIDE + c0);
      float4 x1 = *(const float4*)(sC + rel * CSTRIDE + c0 + 4);
      uint4 o = make_uint4(pack2h(x0.x, x0.y), pack2h(x0.z, x0.w),
                           pack2h(x1.x, x1.y), pack2h(x1.z, x1.w));
      *(uint4*)(out + (size_t)row * DF + c0) = o;
    }
  }

  int copyOff = (blockIdx.x & (NCOPY - 1)) * DF;
  #pragma unroll
  for (int j = 0; j < 4; j++) {
    float s = colS[j], q = colQ[j];
    s += __shfl_xor(s, 16); q += __shfl_xor(q, 16);
    s += __shfl_xor(s, 32); q += __shfl_xor(q, 32);
    if (quad == 0) {
      int col = (cq * 4 + j) * 16 + mcol;
      atomicAdd(&statS[copyOff + col], s);
      atomicAdd(&statQ[copyOff + col], q);
    }
  }
}

// ---------- finalize BN stats (sum NCOPY copies) into affine a,c ----------
// (used once per non-final layer: a,c consumed by the next layer's k_aggr)
__global__ void k_finalize(const float* __restrict__ s, const float* __restrict__ q,
                           const float* __restrict__ gamma, const float* __restrict__ beta,
                           float* __restrict__ a, float* __restrict__ c, int Nrows) {
  int t = threadIdx.x;
  if (t < DF) {
    float S = 0.f, Q = 0.f;
    #pragma unroll
    for (int i = 0; i < NCOPY; i++) { S += s[i * DF + t]; Q += q[i * DF + t]; }
    float inv_n = 1.0f / (float)Nrows;
    float mean = S * inv_n;
    float var = fmaxf(Q * inv_n - mean * mean, 0.0f);
    float iv = rsqrtf(var + 1e-5f);
    float av = gamma[t] * iv;
    a[t] = av;
    c[t] = beta[t] - mean * av;
  }
}

// ---------- final BN apply, f32 out, fused finalize, grid-stride ----------
__global__ __launch_bounds__(256) void k_bnout_f32(
    const u16* __restrict__ u, const float* __restrict__ S, const float* __restrict__ Q,
    const float* __restrict__ gamma, const float* __restrict__ beta, int Nrows,
    float* __restrict__ out, int n8) {
  __shared__ float sAf[DF], sCf[DF];
  int tid = threadIdx.x;
  if (tid < DF) {
    float Sv = 0.f, Qv = 0.f;
    #pragma unroll
    for (int i = 0; i < NCOPY; i++) { Sv += S[i * DF + tid]; Qv += Q[i * DF + tid]; }
    float inv_n = 1.0f / (float)Nrows;
    float mean = Sv * inv_n;
    float var = fmaxf(Qv * inv_n - mean * mean, 0.0f);
    float iv = rsqrtf(var + 1e-5f);
    float a = gamma[tid] * iv;
    sAf[tid] = a;
    sCf[tid] = beta[tid] - mean * a;
  }
  __syncthreads();
  for (int i = blockIdx.x * 256 + tid; i < n8; i += gridDim.x * 256) {
    int col = (i * 8) & 127;
    float4 a0 = *(const float4*)(sAf + col), a1v = *(const float4*)(sAf + col + 4);
    float4 c0 = *(const float4*)(sCf + col), c1v = *(const float4*)(sCf + col + 4);
    uint4 v = ((const uint4*)u)[i];
    float2 f0 = __half22float2(u2h2(v.x));
    float2 f1 = __half22float2(u2h2(v.y));
    float2 f2 = __half22float2(u2h2(v.z));
    float2 f3 = __half22float2(u2h2(v.w));
    float4 o0, o1;
    o0.x = fmaf(a0.x, f0.x, c0.x);
    o0.y = fmaf(a0.y, f0.y, c0.y);
    o0.z = fmaf(a0.z, f1.x, c0.z);
    o0.w = fmaf(a0.w, f1.y, c0.w);
    o1.x = fmaf(a1v.x, f2.x, c1v.x);
    o1.y = fmaf(a1v.y, f2.y, c1v.y);
    o1.z = fmaf(a1v.z, f3.x, c1v.z);
    o1.w = fmaf(a1v.w, f3.y, c1v.w);
    ((float4*)out)[i * 2] = o0;
    ((float4*)out)[i * 2 + 1] = o1;
  }
}

extern "C" void kernel_launch(void* const* d_in, const int* in_sizes, int n_in,
                              void* d_out, int out_size, void* d_ws, size_t ws_size,
                              hipStream_t stream) {
  const float* x    = (const float*)d_in[0];
  const int*   ei   = (const int*)d_in[1];
  const float* W1   = (const float*)d_in[2];
  const float* b1   = (const float*)d_in[3];
  const float* g1   = (const float*)d_in[4];
  const float* bt1  = (const float*)d_in[5];
  const float* W2   = (const float*)d_in[6];
  const float* b2   = (const float*)d_in[7];
  const float* eps  = (const float*)d_in[8];
  const float* gout = (const float*)d_in[9];
  const float* btout= (const float*)d_in[10];

  int N = in_sizes[0] / DF;
  int E = in_sizes[1] / 2;
  int L = in_sizes[8];

  char* ws = (char*)d_ws;
  size_t off = 0;
  auto alloc = [&](size_t bytes) -> void* {
    void* p = ws + off;
    off += (bytes + 255) & ~(size_t)255;
    return p;
  };
  u16* Xb     = (u16*)alloc((size_t)N * DF * 2);
  u16* bufA   = (u16*)alloc((size_t)N * DF * 2);
  u16* bufB   = (u16*)alloc((size_t)N * DF * 2);
  int* rowptr = (int*)alloc((size_t)(N + 1) * 4);
  int* adj    = (int*)alloc((size_t)E * 4);
  uint2* part = (uint2*)alloc((size_t)E * 8);
  int* bCount = (int*)alloc(NBUCK * 4);
  int* bStart = (int*)alloc((NBUCK + 1) * 4);
  int* bCur   = (int*)alloc(NBUCK * 4);
  u16* W1b    = (u16*)alloc((size_t)L * DF * DF * 2);
  u16* W2b    = (u16*)alloc((size_t)L * DF * DF * 2);
  float* stats= (float*)alloc((size_t)L * 4 * STATW * 4);
  float* coefs= (float*)alloc((size_t)L * 4 * DF * 4);

  hipMemsetAsync(bCount, 0, NBUCK * 4, stream);
  hipMemsetAsync(stats, 0, (size_t)L * 4 * STATW * 4, stream);

  int n4x = N * DF / 4;
  k_cvt_f32_f16<<<(n4x + 255) / 256, 256, 0, stream>>>(x, Xb, n4x);
  int n4w = L * DF * DF / 4;
  k_cvt_f32_f16<<<(n4w + 255) / 256, 256, 0, stream>>>(W1, W1b, n4w);
  k_cvt_f32_f16<<<(n4w + 255) / 256, 256, 0, stream>>>(W2, W2b, n4w);

  const int* srcI = ei;
  const int* dstI = ei + E;
  int nbuckets = (N + BUCK_SIZE - 1) >> BUCK_SHIFT;
  k_p1<<<512, 256, 0, stream>>>(dstI, bCount, E);
  k_pscan<<<1, 256, 0, stream>>>(bCount, bStart, bCur, rowptr, N, E);
  k_p2<<<(E + P2_CHUNK - 1) / P2_CHUNK, 256, 0, stream>>>(srcI, dstI, bCur, part, E);
  k_p3<<<nbuckets, 256, 0, stream>>>(part, bStart, rowptr, adj, N);

  // Buffer plan per layer l (z/t/u ping-pong, fused inter-layer BN in aggr):
  //   l even: aggr: H -> bufA(z); gemm1: bufA -> bufB(t); gemm2: bufB -> bufA(u)
  //   l odd : aggr: H -> bufB(z); gemm1: bufB -> bufA(t); gemm2: bufA -> bufB(u)
  int gblocks = (N + 127) / 128;
  int n8 = N * DF / 8;
  const u16* Hcur = Xb;
  const float* aPrev = nullptr;
  const float* cPrev = nullptr;
  int selfRelu = 0;
  for (int l = 0; l < L; l++) {
    float* S1 = stats + (size_t)(l * 4 + 0) * STATW;
    float* Q1 = stats + (size_t)(l * 4 + 1) * STATW;
    float* S2 = stats + (size_t)(l * 4 + 2) * STATW;
    float* Q2 = stats + (size_t)(l * 4 + 3) * STATW;
    float* a2 = coefs + (size_t)(l * 4 + 2) * DF;
    float* c2 = coefs + (size_t)(l * 4 + 3) * DF;
    u16* z = (l & 1) ? bufB : bufA;
    u16* t = (l & 1) ? bufA : bufB;
    u16* u = z;  // z is dead once gemm1 consumed it

    // z = (1+eps)*t_self(H) + sum t(H[src]),  t = relu(a*. + c)
    k_aggr<<<(N + 3) / 4, 256, 0, stream>>>(Hcur, rowptr, adj, eps, l,
                                            aPrev, cPrev, selfRelu, z, N);
    // t = z @ W1^T + b1, stats S1/Q1
    k_gemm<<<gblocks, 256, 0, stream>>>(z, W1b + l * DF * DF, b1 + l * DF,
                                        nullptr, nullptr, nullptr, nullptr, 0,
                                        S1, Q1, t, N);
    // u = relu(BN1(t)) @ W2^T + b2 (BN1 finalize fused in preamble), stats S2/Q2
    k_gemm<<<gblocks, 256, 0, stream>>>(t, W2b + l * DF * DF, b2 + l * DF,
                                        S1, Q1, g1 + l * DF, bt1 + l * DF, 1,
                                        S2, Q2, u, N);
    if (l < L - 1) {
      // outer-BN coefs for the next layer's fused aggr
      k_finalize<<<1, 128, 0, stream>>>(S2, Q2, gout + l * DF, btout + l * DF, a2, c2, N);
      aPrev = a2; cPrev = c2; selfRelu = 1;
      Hcur = u;
    } else {
      k_bnout_f32<<<2048, 256, 0, stream>>>(u, S2, Q2, gout + l * DF, btout + l * DF,
                                            N, (float*)d_out, n8);
    }
  }
}

// Round 11
// 365.523 us; speedup vs baseline: 1.1763x; 1.0141x over previous
//
#include <hip/hip_runtime.h>
#include <hip/hip_fp16.h>

typedef unsigned int u32;
typedef unsigned short u16;
typedef __attribute__((ext_vector_type(8))) _Float16 f16x8;  // 8 fp16 in 4 VGPRs
typedef __attribute__((ext_vector_type(4))) float f32x4;

#define DF 128
#define NBUCK 256          // max buckets (dst >> 9), N=100k -> 196 used
#define BUCK_SHIFT 9
#define BUCK_SIZE 512
#define P2_CHUNK 4096      // 16 edges per thread, 256 threads
#define NCOPY 16           // stat atomic spreading factor
#define STATW (NCOPY * DF)
#define CSTRIDE 132        // f32 stride for C staging (16B-aligned rows, ~2-way banks)

__device__ __forceinline__ __half2 u2h2(u32 x) { union { u32 u; __half2 h; } v; v.u = x; return v.h; }
__device__ __forceinline__ u32 h22u(__half2 h) { union { u32 u; __half2 h; } v; v.h = h; return v.u; }
__device__ __forceinline__ u32 pack2h(float a, float b) { return h22u(__floats2half2_rn(a, b)); }

// packed fp16 max via v_pk_max_f16 (ROCm 7.2 hip_fp16.h lacks __hmax2 on this target)
__device__ __forceinline__ u32 pkmax_u(u32 a, u32 b) {
  u32 r;
  asm("v_pk_max_f16 %0, %1, %2" : "=v"(r) : "v"(a), "v"(b));
  return r;
}
__device__ __forceinline__ __half2 hmax2(__half2 a, __half2 b) {
  return u2h2(pkmax_u(h22u(a), h22u(b)));
}

// ---------- generic f32 -> fp16 conversion (x, W1, W2) ----------
__global__ void k_cvt_f32_f16(const float* __restrict__ in, u16* __restrict__ out, int n4) {
  int i = blockIdx.x * blockDim.x + threadIdx.x;
  if (i >= n4) return;
  float4 v = ((const float4*)in)[i];
  ((uint2*)out)[i] = make_uint2(pack2h(v.x, v.y), pack2h(v.z, v.w));
}

// ---------- CSR build via bucketed counting sort ----------
__global__ __launch_bounds__(256) void k_p1(const int* __restrict__ dst,
                                            int* __restrict__ bucketCount, int E) {
  __shared__ int h[NBUCK];
  int t = threadIdx.x;
  h[t] = 0;
  __syncthreads();
  for (int e = blockIdx.x * 256 + t; e < E; e += gridDim.x * 256)
    atomicAdd(&h[((u32)dst[e]) >> BUCK_SHIFT], 1);
  __syncthreads();
  if (h[t]) atomicAdd(&bucketCount[t], h[t]);
}

__global__ __launch_bounds__(256) void k_pscan(const int* __restrict__ bucketCount,
                                               int* __restrict__ bucketStart,
                                               int* __restrict__ bucketCursor,
                                               int* __restrict__ rowptr, int N, int E) {
  __shared__ int sh[NBUCK];
  int t = threadIdx.x;
  int c = bucketCount[t];
  sh[t] = c;
  __syncthreads();
  for (int o = 1; o < 256; o <<= 1) {
    int v = (t >= o) ? sh[t - o] : 0;
    __syncthreads();
    sh[t] += v;
    __syncthreads();
  }
  int excl = sh[t] - c;
  bucketStart[t] = excl;
  bucketCursor[t] = excl;
  if (t == 255) { bucketStart[256] = sh[255]; rowptr[N] = E; }
}

__global__ __launch_bounds__(256) void k_p2(const int* __restrict__ src,
                                            const int* __restrict__ dst,
                                            int* __restrict__ bucketCursor,
                                            uint2* __restrict__ part, int E) {
  __shared__ int h[NBUCK], hs[NBUCK], base[NBUCK];
  __shared__ int total;
  __shared__ uint2 buf[P2_CHUNK];
  int t = threadIdx.x;
  int e0 = blockIdx.x * P2_CHUNK;
  h[t] = 0;
  __syncthreads();
  int myb[16], myr[16];
  uint2 mye[16];
  #pragma unroll
  for (int k = 0; k < 16; k++) {
    int e = e0 + k * 256 + t;
    myb[k] = -1;
    if (e < E) {
      int s = src[e], d = dst[e];
      mye[k] = make_uint2((u32)s, (u32)d);
      myb[k] = ((u32)d) >> BUCK_SHIFT;
      myr[k] = atomicAdd(&h[myb[k]], 1);
    }
  }
  __syncthreads();
  int hc = h[t];
  hs[t] = hc;
  __syncthreads();
  for (int o = 1; o < 256; o <<= 1) {
    int v = (t >= o) ? hs[t - o] : 0;
    __syncthreads();
    hs[t] += v;
    __syncthreads();
  }
  if (t == 255) total = hs[255];
  int excl = hs[t] - hc;
  base[t] = hc ? atomicAdd(&bucketCursor[t], hc) : 0;
  __syncthreads();
  hs[t] = excl;
  __syncthreads();
  #pragma unroll
  for (int k = 0; k < 16; k++)
    if (myb[k] >= 0) buf[hs[myb[k]] + myr[k]] = mye[k];
  __syncthreads();
  int tot = total;
  for (int i = t; i < tot; i += 256) {
    uint2 ed = buf[i];
    int b = ed.y >> BUCK_SHIFT;
    part[base[b] + (i - hs[b])] = ed;
  }
}

__global__ __launch_bounds__(256) void k_p3(const uint2* __restrict__ part,
                                            const int* __restrict__ bucketStart,
                                            int* __restrict__ rowptr,
                                            int* __restrict__ adj, int N) {
  __shared__ int deg[BUCK_SIZE], cur[BUCK_SIZE], psum[256];
  int b = blockIdx.x, t = threadIdx.x;
  int nodeBase = b << BUCK_SHIFT;
  int eb = bucketStart[b], ee = bucketStart[b + 1];
  deg[t] = 0; deg[t + 256] = 0;
  __syncthreads();
  for (int e = eb + t; e < ee; e += 256)
    atomicAdd(&deg[(int)part[e].y - nodeBase], 1);
  __syncthreads();
  int a0 = deg[2 * t], a1 = deg[2 * t + 1];
  psum[t] = a0 + a1;
  __syncthreads();
  for (int o = 1; o < 256; o <<= 1) {
    int v = (t >= o) ? psum[t - o] : 0;
    __syncthreads();
    psum[t] += v;
    __syncthreads();
  }
  int basep = psum[t] - (a0 + a1);
  int p0 = eb + basep, p1 = eb + basep + a0;
  cur[2 * t] = p0; cur[2 * t + 1] = p1;
  int n0 = nodeBase + 2 * t, n1 = nodeBase + 2 * t + 1;
  if (n0 < N) rowptr[n0] = p0;
  if (n1 < N) rowptr[n1] = p1;
  __syncthreads();
  for (int e = eb + t; e < ee; e += 256) {
    uint2 ed = part[e];
    int pos = atomicAdd(&cur[(int)ed.y - nodeBase], 1);
    adj[pos] = (int)ed.x;
  }
}

// ---------- aggregation with fused inter-layer BN+ReLU (packed fp16) ----------
// Input hin is the PRE-BN activation u of the previous stage (or Xb at l=0).
// Effective node feature: t(v) = relu(a*v + c)   (a=1,c=0 at l=0; selfRelu=0 at l=0)
//   z = (1+eps)*t_self(hin[n]) + sum_{e:dst==n} t(hin[src])
// Neighbor transform+accumulate runs fully packed (v_pk_fma/max/add_f16).
// Masked slots load 0 contributing max(c,0); counted in inv, subtracted packed.
// 16 neighbors per iteration (4 gathers in flight per lane) for MLP depth;
// deg<=16 (~97% of nodes at mean 10) completes in one iteration.
__global__ void k_aggr(const u16* __restrict__ hin,
                       const int* __restrict__ rowptr, const int* __restrict__ adj,
                       const float* __restrict__ epsArr, int layer,
                       const float* __restrict__ aAff, const float* __restrict__ cAff,
                       int selfRelu,
                       u16* __restrict__ z, int N) {
  int wid = (blockIdx.x * blockDim.x + threadIdx.x) >> 6;
  if (wid >= N) return;
  int lane = threadIdx.x & 63;
  int g = lane >> 4, f = lane & 15;          // neighbor slot, feature group
  const uint4* h4 = (const uint4*)hin;
  float e1 = 1.0f + epsArr[layer];
  __half2 zero2 = __floats2half2_rn(0.0f, 0.0f);

  float av[8], cv[8];
  if (aAff) {
    float4 a0 = *(const float4*)(aAff + f * 8);
    float4 a1 = *(const float4*)(aAff + f * 8 + 4);
    float4 c0 = *(const float4*)(cAff + f * 8);
    float4 c1 = *(const float4*)(cAff + f * 8 + 4);
    av[0] = a0.x; av[1] = a0.y; av[2] = a0.z; av[3] = a0.w;
    av[4] = a1.x; av[5] = a1.y; av[6] = a1.z; av[7] = a1.w;
    cv[0] = c0.x; cv[1] = c0.y; cv[2] = c0.z; cv[3] = c0.w;
    cv[4] = c1.x; cv[5] = c1.y; cv[6] = c1.z; cv[7] = c1.w;
  } else {
    #pragma unroll
    for (int k = 0; k < 8; k++) { av[k] = 1.0f; cv[k] = 0.0f; }
  }
  __half2 a2[4], c2[4], cm2[4], acc2[4];
  #pragma unroll
  for (int k = 0; k < 4; k++) {
    a2[k] = __floats2half2_rn(av[2 * k], av[2 * k + 1]);
    c2[k] = __floats2half2_rn(cv[2 * k], cv[2 * k + 1]);
    cm2[k] = hmax2(c2[k], zero2);
    acc2[k] = zero2;
  }

  int b = rowptr[wid], e = rowptr[wid + 1];
  int inv = 0;
  for (int p = b; p < e; p += 16) {
    int i0 = p + g, i1 = p + 4 + g, i2 = p + 8 + g, i3 = p + 12 + g;
    uint4 v0 = make_uint4(0, 0, 0, 0), v1 = make_uint4(0, 0, 0, 0);
    uint4 v2 = make_uint4(0, 0, 0, 0), v3 = make_uint4(0, 0, 0, 0);
    if (i0 < e) v0 = h4[(size_t)(u32)adj[i0] * 16 + f]; else inv++;
    if (i1 < e) v1 = h4[(size_t)(u32)adj[i1] * 16 + f]; else inv++;
    if (i2 < e) v2 = h4[(size_t)(u32)adj[i2] * 16 + f]; else inv++;
    if (i3 < e) v3 = h4[(size_t)(u32)adj[i3] * 16 + f]; else inv++;
    u32 w0[4] = {v0.x, v0.y, v0.z, v0.w};
    u32 w1[4] = {v1.x, v1.y, v1.z, v1.w};
    u32 w2[4] = {v2.x, v2.y, v2.z, v2.w};
    u32 w3[4] = {v3.x, v3.y, v3.z, v3.w};
    #pragma unroll
    for (int k = 0; k < 4; k++) {
      acc2[k] = __hadd2(acc2[k], hmax2(__hfma2(a2[k], u2h2(w0[k]), c2[k]), zero2));
      acc2[k] = __hadd2(acc2[k], hmax2(__hfma2(a2[k], u2h2(w1[k]), c2[k]), zero2));
      acc2[k] = __hadd2(acc2[k], hmax2(__hfma2(a2[k], u2h2(w2[k]), c2[k]), zero2));
      acc2[k] = __hadd2(acc2[k], hmax2(__hfma2(a2[k], u2h2(w3[k]), c2[k]), zero2));
    }
  }
  // remove contribution of zero-filled invalid slots (each added max(c,0)),
  // then reduce across the 4 neighbor slots, all packed
  __half2 inv2 = __floats2half2_rn((float)inv, (float)inv);
  #pragma unroll
  for (int k = 0; k < 4; k++) {
    acc2[k] = __hsub2(acc2[k], __hmul2(inv2, cm2[k]));
    acc2[k] = __hadd2(acc2[k], u2h2(__shfl_xor(h22u(acc2[k]), 16)));
    acc2[k] = __hadd2(acc2[k], u2h2(__shfl_xor(h22u(acc2[k]), 32)));
  }

  if (g == 0) {
    uint4 sv = h4[(size_t)wid * 16 + f];
    u32 sw[4] = {sv.x, sv.y, sv.z, sv.w};
    u32 o[4];
    #pragma unroll
    for (int k = 0; k < 4; k++) {
      float2 s = __half22float2(u2h2(sw[k]));
      float lo = fmaf(av[2 * k], s.x, cv[2 * k]);
      float hi = fmaf(av[2 * k + 1], s.y, cv[2 * k + 1]);
      if (selfRelu) { lo = fmaxf(lo, 0.0f); hi = fmaxf(hi, 0.0f); }
      float2 nb = __half22float2(acc2[k]);
      o[k] = pack2h(fmaf(e1, lo, nb.x), fmaf(e1, hi, nb.y));
    }
    ((uint4*)z)[(size_t)wid * 16 + f] = make_uint4(o[0], o[1], o[2], o[3]);
  }
}

// ---------- GEMM: out[r][c] = sum_k in[r][k] * W[c][k] + bias[c]  (fp16 MFMA) ----------
// trans=1: fused BN finalize preamble computes packed half2 affine into LDS; input
// transform in' = relu(a[k]*in + c[k]) applied packed during A-staging.
// Epilogue: C staged through LDS (f32, stride CSTRIDE) then stored as coalesced
// uint4 (8 stores/thread instead of 64 scalar 2B stores).
// launch_bounds (256,3): 3 blocks/CU resident (12 waves/CU) to hide staging latency.
__global__ __launch_bounds__(256, 3) void k_gemm(
    const u16* __restrict__ A, const u16* __restrict__ W, const float* __restrict__ bias,
    const float* __restrict__ Sprev, const float* __restrict__ Qprev,
    const float* __restrict__ gprev, const float* __restrict__ btprev, int trans,
    float* __restrict__ statS, float* __restrict__ statQ,
    u16* __restrict__ out, int Nrows) {
  __shared__ __align__(16) char smem[128 * CSTRIDE * 4 + 512];
  u16* lA = (u16*)smem;                       // 32 KB (A tile, fp16)
  u16* lB = (u16*)(smem + 32768);             // 32 KB (B tile, fp16)
  float* sC = (float*)smem;                   // 128 x CSTRIDE f32 (epilogue reuse)
  __half2* sA2 = (__half2*)(smem + 128 * CSTRIDE * 4);        // 64 half2
  __half2* sC2 = (__half2*)(smem + 128 * CSTRIDE * 4 + 256);  // 64 half2
  int tid = threadIdx.x;
  int rowBase = blockIdx.x * 128;

  if (trans) {
    if (tid < 64) {
      float aa[2], cc[2];
      #pragma unroll
      for (int j = 0; j < 2; j++) {
        int col = tid * 2 + j;
        float Sv = 0.f, Qv = 0.f;
        #pragma unroll
        for (int i = 0; i < NCOPY; i++) { Sv += Sprev[i * DF + col]; Qv += Qprev[i * DF + col]; }
        float inv_n = 1.0f / (float)Nrows;
        float mean = Sv * inv_n;
        float var = fmaxf(Qv * inv_n - mean * mean, 0.0f);
        float iv = rsqrtf(var + 1e-5f);
        float a = gprev[col] * iv;
        aa[j] = a;
        cc[j] = btprev[col] - mean * a;
      }
      sA2[tid] = __floats2half2_rn(aa[0], aa[1]);
      sC2[tid] = __floats2half2_rn(cc[0], cc[1]);
    }
    __syncthreads();
  }

  // stage A (z rows) in fragment order
  #pragma unroll
  for (int cc = 0; cc < 8; cc++) {
    int c = tid + cc * 256;
    int lane = c & 63, rt = (c >> 6) & 7, kt = c >> 9;
    int m = lane & 15, quad = lane >> 4;
    int grow = rowBase + rt * 16 + m;
    int gk = kt * 32 + quad * 8;
    uint4 val = make_uint4(0, 0, 0, 0);
    if (grow < Nrows) val = *(const uint4*)(A + (size_t)grow * DF + gk);
    if (trans) {
      uint4 aw = ((const uint4*)sA2)[gk >> 3];
      uint4 cw = ((const uint4*)sC2)[gk >> 3];
      val.x = pkmax_u(h22u(__hfma2(u2h2(aw.x), u2h2(val.x), u2h2(cw.x))), 0u);
      val.y = pkmax_u(h22u(__hfma2(u2h2(aw.y), u2h2(val.y), u2h2(cw.y))), 0u);
      val.z = pkmax_u(h22u(__hfma2(u2h2(aw.z), u2h2(val.z), u2h2(cw.z))), 0u);
      val.w = pkmax_u(h22u(__hfma2(u2h2(aw.w), u2h2(val.w), u2h2(cw.w))), 0u);
    }
    ((uint4*)lA)[c] = val;
  }
  // stage B (W rows, [c][k]) in fragment order
  #pragma unroll
  for (int cc = 0; cc < 8; cc++) {
    int c = tid + cc * 256;
    int lane = c & 63, ct = (c >> 6) & 7, kt = c >> 9;
    int n = lane & 15, quad = lane >> 4;
    ((uint4*)lB)[c] = *(const uint4*)(W + (ct * 16 + n) * DF + kt * 32 + quad * 8);
  }
  __syncthreads();

  int lane = tid & 63, w = tid >> 6;
  int rq = w >> 1, cq = w & 1;  // wave -> 64x64 quadrant
  f32x4 acc[4][4];
  #pragma unroll
  for (int i = 0; i < 4; i++)
    #pragma unroll
    for (int j = 0; j < 4; j++) acc[i][j] = (f32x4){0.f, 0.f, 0.f, 0.f};

  const f16x8* pA = (const f16x8*)lA;
  const f16x8* pB = (const f16x8*)lB;
  #pragma unroll
  for (int kt = 0; kt < 4; kt++) {
    f16x8 af[4], bfr[4];
    #pragma unroll
    for (int i = 0; i < 4; i++) af[i] = pA[(kt * 8 + rq * 4 + i) * 64 + lane];
    #pragma unroll
    for (int j = 0; j < 4; j++) bfr[j] = pB[(kt * 8 + cq * 4 + j) * 64 + lane];
    #pragma unroll
    for (int i = 0; i < 4; i++)
      #pragma unroll
      for (int j = 0; j < 4; j++)
        acc[i][j] = __builtin_amdgcn_mfma_f32_16x16x32_f16(af[i], bfr[j], acc[i][j], 0, 0, 0);
  }

  __syncthreads();   // all LDS A/B reads done; safe to overwrite with C

  // epilogue: bias + per-column stats, C -> LDS (f32)
  int mcol = lane & 15, quad = lane >> 4;
  float colS[4] = {0, 0, 0, 0}, colQ[4] = {0, 0, 0, 0};
  #pragma unroll
  for (int j = 0; j < 4; j++) {
    int col = (cq * 4 + j) * 16 + mcol;
    float bv = bias[col];
    #pragma unroll
    for (int i = 0; i < 4; i++) {
      int rel0 = (rq * 4 + i) * 16 + quad * 4;
      #pragma unroll
      for (int r = 0; r < 4; r++) {
        int rel = rel0 + r;
        float v = acc[i][j][r] + bv;
        sC[rel * CSTRIDE + col] = v;
        if (rowBase + rel < Nrows) { colS[j] += v; colQ[j] += v * v; }
      }
    }
  }
  __syncthreads();

  // readout: coalesced fp16 uint4 stores (8 per thread)
  #pragma unroll
  for (int k = 0; k < 8; k++) {
    int idx = k * 256 + tid;          // uint4 index within 128x128 tile
    int rel = idx >> 4;
    int c0 = (idx & 15) * 8;
    int row = rowBase + rel;
    if (row < Nrows) {
      float4 x0 = *(const float4*)(sC + rel * CSTRIDE + c0);
      float4 x1 = *(const float4*)(sC + rel * CSTRIDE + c0 + 4);
      uint4 o = make_uint4(pack2h(x0.x, x0.y), pack2h(x0.z, x0.w),
                           pack2h(x1.x, x1.y), pack2h(x1.z, x1.w));
      *(uint4*)(out + (size_t)row * DF + c0) = o;
    }
  }

  int copyOff = (blockIdx.x & (NCOPY - 1)) * DF;
  #pragma unroll
  for (int j = 0; j < 4; j++) {
    float s = colS[j], q = colQ[j];
    s += __shfl_xor(s, 16); q += __shfl_xor(q, 16);
    s += __shfl_xor(s, 32); q += __shfl_xor(q, 32);
    if (quad == 0) {
      int col = (cq * 4 + j) * 16 + mcol;
      atomicAdd(&statS[copyOff + col], s);
      atomicAdd(&statQ[copyOff + col], q);
    }
  }
}

// ---------- finalize BN stats (sum NCOPY copies) into affine a,c ----------
// (used once per non-final layer: a,c consumed by the next layer's k_aggr)
__global__ void k_finalize(const float* __restrict__ s, const float* __restrict__ q,
                           const float* __restrict__ gamma, const float* __restrict__ beta,
                           float* __restrict__ a, float* __restrict__ c, int Nrows) {
  int t = threadIdx.x;
  if (t < DF) {
    float S = 0.f, Q = 0.f;
    #pragma unroll
    for (int i = 0; i < NCOPY; i++) { S += s[i * DF + t]; Q += q[i * DF + t]; }
    float inv_n = 1.0f / (float)Nrows;
    float mean = S * inv_n;
    float var = fmaxf(Q * inv_n - mean * mean, 0.0f);
    float iv = rsqrtf(var + 1e-5f);
    float av = gamma[t] * iv;
    a[t] = av;
    c[t] = beta[t] - mean * av;
  }
}

// ---------- final BN apply, f32 out, fused finalize, grid-stride ----------
__global__ __launch_bounds__(256) void k_bnout_f32(
    const u16* __restrict__ u, const float* __restrict__ S, const float* __restrict__ Q,
    const float* __restrict__ gamma, const float* __restrict__ beta, int Nrows,
    float* __restrict__ out, int n8) {
  __shared__ float sAf[DF], sCf[DF];
  int tid = threadIdx.x;
  if (tid < DF) {
    float Sv = 0.f, Qv = 0.f;
    #pragma unroll
    for (int i = 0; i < NCOPY; i++) { Sv += S[i * DF + tid]; Qv += Q[i * DF + tid]; }
    float inv_n = 1.0f / (float)Nrows;
    float mean = Sv * inv_n;
    float var = fmaxf(Qv * inv_n - mean * mean, 0.0f);
    float iv = rsqrtf(var + 1e-5f);
    float a = gamma[tid] * iv;
    sAf[tid] = a;
    sCf[tid] = beta[tid] - mean * a;
  }
  __syncthreads();
  for (int i = blockIdx.x * 256 + tid; i < n8; i += gridDim.x * 256) {
    int col = (i * 8) & 127;
    float4 a0 = *(const float4*)(sAf + col), a1v = *(const float4*)(sAf + col + 4);
    float4 c0 = *(const float4*)(sCf + col), c1v = *(const float4*)(sCf + col + 4);
    uint4 v = ((const uint4*)u)[i];
    float2 f0 = __half22float2(u2h2(v.x));
    float2 f1 = __half22float2(u2h2(v.y));
    float2 f2 = __half22float2(u2h2(v.z));
    float2 f3 = __half22float2(u2h2(v.w));
    float4 o0, o1;
    o0.x = fmaf(a0.x, f0.x, c0.x);
    o0.y = fmaf(a0.y, f0.y, c0.y);
    o0.z = fmaf(a0.z, f1.x, c0.z);
    o0.w = fmaf(a0.w, f1.y, c0.w);
    o1.x = fmaf(a1v.x, f2.x, c1v.x);
    o1.y = fmaf(a1v.y, f2.y, c1v.y);
    o1.z = fmaf(a1v.z, f3.x, c1v.z);
    o1.w = fmaf(a1v.w, f3.y, c1v.w);
    ((float4*)out)[i * 2] = o0;
    ((float4*)out)[i * 2 + 1] = o1;
  }
}

extern "C" void kernel_launch(void* const* d_in, const int* in_sizes, int n_in,
                              void* d_out, int out_size, void* d_ws, size_t ws_size,
                              hipStream_t stream) {
  const float* x    = (const float*)d_in[0];
  const int*   ei   = (const int*)d_in[1];
  const float* W1   = (const float*)d_in[2];
  const float* b1   = (const float*)d_in[3];
  const float* g1   = (const float*)d_in[4];
  const float* bt1  = (const float*)d_in[5];
  const float* W2   = (const float*)d_in[6];
  const float* b2   = (const float*)d_in[7];
  const float* eps  = (const float*)d_in[8];
  const float* gout = (const float*)d_in[9];
  const float* btout= (const float*)d_in[10];

  int N = in_sizes[0] / DF;
  int E = in_sizes[1] / 2;
  int L = in_sizes[8];

  char* ws = (char*)d_ws;
  size_t off = 0;
  auto alloc = [&](size_t bytes) -> void* {
    void* p = ws + off;
    off += (bytes + 255) & ~(size_t)255;
    return p;
  };
  u16* Xb     = (u16*)alloc((size_t)N * DF * 2);
  u16* bufA   = (u16*)alloc((size_t)N * DF * 2);
  u16* bufB   = (u16*)alloc((size_t)N * DF * 2);
  int* rowptr = (int*)alloc((size_t)(N + 1) * 4);
  int* adj    = (int*)alloc((size_t)E * 4);
  uint2* part = (uint2*)alloc((size_t)E * 8);
  int* bCount = (int*)alloc(NBUCK * 4);
  int* bStart = (int*)alloc((NBUCK + 1) * 4);
  int* bCur   = (int*)alloc(NBUCK * 4);
  u16* W1b    = (u16*)alloc((size_t)L * DF * DF * 2);
  u16* W2b    = (u16*)alloc((size_t)L * DF * DF * 2);
  float* stats= (float*)alloc((size_t)L * 4 * STATW * 4);
  float* coefs= (float*)alloc((size_t)L * 4 * DF * 4);

  hipMemsetAsync(bCount, 0, NBUCK * 4, stream);
  hipMemsetAsync(stats, 0, (size_t)L * 4 * STATW * 4, stream);

  int n4x = N * DF / 4;
  k_cvt_f32_f16<<<(n4x + 255) / 256, 256, 0, stream>>>(x, Xb, n4x);
  int n4w = L * DF * DF / 4;
  k_cvt_f32_f16<<<(n4w + 255) / 256, 256, 0, stream>>>(W1, W1b, n4w);
  k_cvt_f32_f16<<<(n4w + 255) / 256, 256, 0, stream>>>(W2, W2b, n4w);

  const int* srcI = ei;
  const int* dstI = ei + E;
  int nbuckets = (N + BUCK_SIZE - 1) >> BUCK_SHIFT;
  k_p1<<<512, 256, 0, stream>>>(dstI, bCount, E);
  k_pscan<<<1, 256, 0, stream>>>(bCount, bStart, bCur, rowptr, N, E);
  k_p2<<<(E + P2_CHUNK - 1) / P2_CHUNK, 256, 0, stream>>>(srcI, dstI, bCur, part, E);
  k_p3<<<nbuckets, 256, 0, stream>>>(part, bStart, rowptr, adj, N);

  // Buffer plan per layer l (z/t/u ping-pong, fused inter-layer BN in aggr):
  //   l even: aggr: H -> bufA(z); gemm1: bufA -> bufB(t); gemm2: bufB -> bufA(u)
  //   l odd : aggr: H -> bufB(z); gemm1: bufB -> bufA(t); gemm2: bufA -> bufB(u)
  int gblocks = (N + 127) / 128;
  int n8 = N * DF / 8;
  const u16* Hcur = Xb;
  const float* aPrev = nullptr;
  const float* cPrev = nullptr;
  int selfRelu = 0;
  for (int l = 0; l < L; l++) {
    float* S1 = stats + (size_t)(l * 4 + 0) * STATW;
    float* Q1 = stats + (size_t)(l * 4 + 1) * STATW;
    float* S2 = stats + (size_t)(l * 4 + 2) * STATW;
    float* Q2 = stats + (size_t)(l * 4 + 3) * STATW;
    float* a2 = coefs + (size_t)(l * 4 + 2) * DF;
    float* c2 = coefs + (size_t)(l * 4 + 3) * DF;
    u16* z = (l & 1) ? bufB : bufA;
    u16* t = (l & 1) ? bufA : bufB;
    u16* u = z;  // z is dead once gemm1 consumed it

    // z = (1+eps)*t_self(H) + sum t(H[src]),  t = relu(a*. + c)
    k_aggr<<<(N + 3) / 4, 256, 0, stream>>>(Hcur, rowptr, adj, eps, l,
                                            aPrev, cPrev, selfRelu, z, N);
    // t = z @ W1^T + b1, stats S1/Q1
    k_gemm<<<gblocks, 256, 0, stream>>>(z, W1b + l * DF * DF, b1 + l * DF,
                                        nullptr, nullptr, nullptr, nullptr, 0,
                                        S1, Q1, t, N);
    // u = relu(BN1(t)) @ W2^T + b2 (BN1 finalize fused in preamble), stats S2/Q2
    k_gemm<<<gblocks, 256, 0, stream>>>(t, W2b + l * DF * DF, b2 + l * DF,
                                        S1, Q1, g1 + l * DF, bt1 + l * DF, 1,
                                        S2, Q2, u, N);
    if (l < L - 1) {
      // outer-BN coefs for the next layer's fused aggr
      k_finalize<<<1, 128, 0, stream>>>(S2, Q2, gout + l * DF, btout + l * DF, a2, c2, N);
      aPrev = a2; cPrev = c2; selfRelu = 1;
      Hcur = u;
    } else {
      k_bnout_f32<<<2048, 256, 0, stream>>>(u, S2, Q2, gout + l * DF, btout + l * DF,
                                            N, (float*)d_out, n8);
    }
  }
}